// Round 15
// baseline (61.901 us; speedup 1.0000x reference)
//
#include <hip/hip_runtime.h>

#define NN 4194304
#define NB 16384
#define GRIDP 768    // persistent grid: 3 blocks/CU x 256 CU
#define NUNITS 4096  // units of 1024 nodes (4 nodes/thread)

typedef _Float16 half4 __attribute__((ext_vector_type(4)));
typedef float floatx4 __attribute__((ext_vector_type(4)));
typedef unsigned int uint;

__device__ __forceinline__ uint pk_u32(float lo, float hi) {
  return __builtin_bit_cast(uint, __builtin_amdgcn_cvt_pkrtz(lo, hi));
}

__device__ __forceinline__ half4 relu_cvt(floatx4 d) {
  uint2 u;
  u.x = pk_u32(d[0], d[1]);
  u.y = pk_u32(d[2], d[3]);
  half4 h = __builtin_bit_cast(half4, u);
  return __builtin_elementwise_max(h, half4{0, 0, 0, 0});
}

// DPP butterfly wave64 sum; total lands in lane 63. 6 VALU adds, no LDS.
template <int CTRL>
__device__ __forceinline__ float dpp_add(float x) {
  int y = __builtin_amdgcn_update_dpp(0, __builtin_bit_cast(int, x), CTRL,
                                      0xf, 0xf, true);
  return x + __builtin_bit_cast(float, y);
}
__device__ __forceinline__ float wave_sum(float x) {
  x = dpp_add<0x111>(x);
  x = dpp_add<0x112>(x);
  x = dpp_add<0x114>(x);
  x = dpp_add<0x118>(x);
  x = dpp_add<0x142>(x);
  x = dpp_add<0x143>(x);
  return x;
}

// Segmented reduce + atomics. Fast path: wave-uniform segment (avg run = 256).
__device__ __forceinline__ void seg_atomic_add2(int b, float vx, float vy,
                                                float* __restrict__ out) {
  const int lane = threadIdx.x & 63;
  int b0 = __builtin_amdgcn_readfirstlane(b);
  if (__ballot(b == b0) == ~0ull) {
    float sx = wave_sum(vx);
    float sy = wave_sum(vy);
    if (lane == 63) {
      atomicAdd(&out[2 * b0], sx);
      atomicAdd(&out[2 * b0 + 1], sy);
    }
    return;
  }
  int bprev = __shfl_up(b, 1);
  bool head = (lane == 0) || (b != bprev);
  unsigned long long hb = __ballot(head);
  unsigned long long mask_le = hb << (63 - lane);
  int run_start = lane - __clzll(mask_le);
  float sx = vx, sy = vy;
#pragma unroll
  for (int off = 1; off < 64; off <<= 1) {
    float ox = __shfl_up(sx, off);
    float oy = __shfl_up(sy, off);
    if (lane - off >= run_start) { sx += ox; sy += oy; }
  }
  int bnext = __shfl_down(b, 1);
  bool tail = (lane == 63) || (b != bnext);
  if (tail) {
    atomicAdd(&out[2 * b], sx);
    atomicAdd(&out[2 * b + 1], sy);
  }
}

// Persistent centroid: grid-stride over units, next unit's loads prefetched.
__global__ __launch_bounds__(256) void centroid_kernel(
    const float2* __restrict__ pos, const int* __restrict__ batch,
    float* __restrict__ csum) {
  const int tid = threadIdx.x;
  int u = blockIdx.x;
  int biA[4];
  float2 pvA[4];
  int base = u * 1024 + tid;
#pragma unroll
  for (int r = 0; r < 4; ++r) {
    biA[r] = batch[base + r * 256];
    pvA[r] = pos[base + r * 256];
  }
  for (; u < NUNITS; u += GRIDP) {
    int un = u + GRIDP;
    int biB[4];
    float2 pvB[4];
    if (un < NUNITS) {
      int nb = un * 1024 + tid;
#pragma unroll
      for (int r = 0; r < 4; ++r) {
        biB[r] = batch[nb + r * 256];
        pvB[r] = pos[nb + r * 256];
      }
    }
#pragma unroll
    for (int r = 0; r < 4; ++r)
      seg_atomic_add2(biA[r], pvA[r].x, pvA[r].y, csum);
    if (un < NUNITS) {
#pragma unroll
      for (int r = 0; r < 4; ++r) { biA[r] = biB[r]; pvA[r] = pvB[r]; }
    }
  }
}

// Prepack weights into A-fragments of mfma_f32_16x16x16f16 (W as A: M=out,K=in).
// ALL biases folded via fake constant-1 neurons (see tile comments).
// Blocks 3..66 zero csum (8192 float4) and out (8192 float4).
__global__ void prepack_kernel(
    const float* __restrict__ W1, const float* __restrict__ W2,
    const float* __restrict__ W3, const float* __restrict__ W4,
    const float* __restrict__ W5, const float* __restrict__ B1,
    const float* __restrict__ B2, const float* __restrict__ B3,
    const float* __restrict__ B4, const float* __restrict__ B5,
    uint2* __restrict__ Wf, float* __restrict__ csum,
    float* __restrict__ out) {
  if (blockIdx.x >= 3) {
    int z = (blockIdx.x - 3) * 256 + threadIdx.x;  // 0..16383
    float4 zero{0.f, 0.f, 0.f, 0.f};
    if (z < 8192) ((float4*)csum)[z] = zero;
    else ((float4*)out)[z - 8192] = zero;
    return;
  }
  int p = blockIdx.x * 256 + threadIdx.x;
  if (p >= 448) return;
  int tile = p >> 6, lane = p & 63, row = lane & 15, kb = (lane >> 4) * 4;
  float v[4];
#pragma unroll
  for (int i = 0; i < 4; ++i) {
    int k = kb + i;
    float x = 0.f;
    switch (tile) {
      case 0:  // W1 (10x3); k=3: B1; row10 = bias-1 neuron
        if (row < 10 && k < 3) x = W1[row * 3 + k];
        if (k == 3) { if (row < 10) x = B1[row]; else if (row == 10) x = 1.f; }
        break;
      case 1:  // W2 rows 0-15; k=10: B2
        if (k < 10) x = W2[row * 10 + k];
        else if (k == 10) x = B2[row];
        break;
      case 2:  // W2 rows 16-19; k=10: B2[16+]; row4 = bias-1
        if (row < 4 && k < 10) x = W2[(16 + row) * 10 + k];
        if (k == 10) { if (row < 4) x = B2[16 + row]; else if (row == 4) x = 1.f; }
        break;
      case 3:  // W3 k0-15
        if (row < 10 && k < 16) x = W3[row * 20 + k];
        break;
      case 4:  // W3 k16-19; local k4: B3; row10 = bias-1
        if (row < 10 && k < 4) x = W3[row * 20 + 16 + k];
        if (k == 4) { if (row < 10) x = B3[row]; else if (row == 10) x = 1.f; }
        break;
      case 5:  // W4; k=10: B4; row5 = bias-1
        if (row < 5 && k < 10) x = W4[row * 10 + k];
        if (k == 10) { if (row < 5) x = B4[row]; else if (row == 5) x = 1.f; }
        break;
      default:  // W5; k=5: B5
        if (row == 0 && k < 5) x = W5[k];
        if (row == 0 && k == 5) x = B5[0];
        break;
    }
    v[i] = x;
  }
  Wf[p] = uint2{pk_u32(v[0], v[1]), pk_u32(v[2], v[3])};
}

__device__ __forceinline__ floatx4 mfma16(half4 a, half4 b, floatx4 c) {
  return __builtin_amdgcn_mfma_f32_16x16x16f16(a, b, c, 0, 0, 0);
}

// Persistent main: weights loaded once per block; per-unit software pipeline:
//   loop top: issue next unit's streaming loads (hidden under MFMA chain)
//   after MFMA: issue next unit's gathers (L2-resident, hidden under epilogue)
__global__ __launch_bounds__(256, 3) void main_kernel(
    const float* __restrict__ t, const float2* __restrict__ pos,
    const float* __restrict__ poi_t, const float2* __restrict__ poi_pos,
    const int* __restrict__ batch, const float2* __restrict__ csum2,
    const uint2* __restrict__ Wf, float* __restrict__ out) {
  const int tid = threadIdx.x;
  const int lane = tid & 63;
  const int col = lane & 15;
  const int koct = lane >> 4;

  // Weight A-fragments (biases folded; loaded ONCE per persistent block).
  half4 wa[7];
#pragma unroll
  for (int k = 0; k < 7; ++k)
    wa[k] = __builtin_bit_cast(half4, Wf[k * 64 + lane]);
  floatx4 cz{0.f, 0.f, 0.f, 0.f};

  // Prologue: streaming loads + gathers for first unit.
  int u = blockIdx.x;
  int biA[4];
  float tvA[4];
  float2 pvA[4];
  {
    int base = u * 1024 + tid;
#pragma unroll
    for (int r = 0; r < 4; ++r) {
      biA[r] = batch[base + r * 256];
      tvA[r] = t[base + r * 256];
      pvA[r] = pos[base + r * 256];
    }
  }
  float2 ppA[4], csA[4];
  float ptA[4];
#pragma unroll
  for (int r = 0; r < 4; ++r) {
    ppA[r] = poi_pos[biA[r]];
    csA[r] = csum2[biA[r]];
    ptA[r] = poi_t[biA[r]];
  }

  for (; u < NUNITS; u += GRIDP) {
    const int un = u + GRIDP;
    const bool hn = (un < NUNITS);

    // Issue next unit's streaming loads NOW (latency hides under MFMA).
    int biB[4];
    float tvB[4];
    float2 pvB[4];
    if (hn) {
      int nb = un * 1024 + tid;
#pragma unroll
      for (int r = 0; r < 4; ++r) {
        biB[r] = batch[nb + r * 256];
        tvB[r] = t[nb + r * 256];
        pvB[r] = pos[nb + r * 256];
      }
    }

    // ---- Features + MLP for current unit (8 MFMA chains per layer) ----
    float dpx[4], dpy[4], f1v[4], invr[4];
    int fx[4], fy[4];
#pragma unroll
    for (int r = 0; r < 4; ++r) {
      float f0 = tvA[r] - ptA[r];
      float dcx = csA[r].x - ppA[r].x;
      float dcy = csA[r].y - ppA[r].y;
      float invc = rsqrtf(dcx * dcx + dcy * dcy);
      dpx[r] = pvA[r].x - ppA[r].x;
      dpy[r] = pvA[r].y - ppA[r].y;
      f1v[r] = dpx[r] * dpx[r] + dpy[r] * dpy[r];
      invr[r] = rsqrtf(f1v[r]);
      float f2 = (dpx[r] * dcx + dpy[r] * dcy) * invc * invr[r];
      fx[r] = (int)pk_u32(f0, f1v[r]);
      fy[r] = (int)pk_u32(f2, 1.0f);  // 1.0 feeds the folded-bias column
    }

    float wv[4];
#pragma unroll
    for (int rp = 0; rp < 2; ++rp) {
      half4 b1[8];
#pragma unroll
      for (int uu = 0; uu < 2; ++uu)
#pragma unroll
        for (int g = 0; g < 4; ++g) {
          int src = g * 16 + col;
          uint2 fr;
          fr.x = (uint)__shfl(fx[rp * 2 + uu], src);
          fr.y = (uint)__shfl(fy[rp * 2 + uu], src);
          b1[uu * 4 + g] = __builtin_bit_cast(half4, fr);
        }

      floatx4 d[8];
      half4 a[8];
#pragma unroll
      for (int c = 0; c < 8; ++c) d[c] = mfma16(wa[0], b1[c], cz);  // L1
#pragma unroll
      for (int c = 0; c < 8; ++c) a[c] = relu_cvt(d[c]);

      floatx4 d2[8];
      half4 a3a[8], a3b[8];
#pragma unroll
      for (int c = 0; c < 8; ++c) d2[c] = mfma16(wa[1], a[c], cz);  // L2a
#pragma unroll
      for (int c = 0; c < 8; ++c) a3a[c] = relu_cvt(d2[c]);
#pragma unroll
      for (int c = 0; c < 8; ++c) d2[c] = mfma16(wa[2], a[c], cz);  // L2b
#pragma unroll
      for (int c = 0; c < 8; ++c) a3b[c] = relu_cvt(d2[c]);

#pragma unroll
      for (int c = 0; c < 8; ++c) d[c] = mfma16(wa[3], a3a[c], cz); // L3a
#pragma unroll
      for (int c = 0; c < 8; ++c) d[c] = mfma16(wa[4], a3b[c], d[c]); // L3b
#pragma unroll
      for (int c = 0; c < 8; ++c) a[c] = relu_cvt(d[c]);

#pragma unroll
      for (int c = 0; c < 8; ++c) d[c] = mfma16(wa[5], a[c], cz);   // L4
#pragma unroll
      for (int c = 0; c < 8; ++c) a[c] = relu_cvt(d[c]);

#pragma unroll
      for (int c = 0; c < 8; ++c) d[c] = mfma16(wa[6], a[c], cz);   // L5

#pragma unroll
      for (int uu = 0; uu < 2; ++uu) {
        float wg0 = __shfl(d[uu * 4 + 0][0], col);
        float wg1 = __shfl(d[uu * 4 + 1][0], col);
        float wg2 = __shfl(d[uu * 4 + 2][0], col);
        float wg3 = __shfl(d[uu * 4 + 3][0], col);
        float w = wg0;
        w = (koct == 1) ? wg1 : w;
        w = (koct == 2) ? wg2 : w;
        w = (koct == 3) ? wg3 : w;
        wv[rp * 2 + uu] = w;
      }
    }

    // Issue next unit's gathers (L2-resident; hides under epilogue).
    float2 ppB[4], csB[4];
    float ptB[4];
    if (hn) {
#pragma unroll
      for (int r = 0; r < 4; ++r) {
        ppB[r] = poi_pos[biB[r]];
        csB[r] = csum2[biB[r]];
        ptB[r] = poi_t[biB[r]];
      }
    }

    // Epilogue: segmented atomic reduction for current unit.
#pragma unroll
    for (int r = 0; r < 4; ++r) {
      float invn = (f1v[r] > 0.f) ? invr[r] : 0.f;
      seg_atomic_add2(biA[r], wv[r] * dpx[r] * invn, wv[r] * dpy[r] * invn,
                      out);
    }

    // Rotate pipeline registers.
    if (hn) {
#pragma unroll
      for (int r = 0; r < 4; ++r) {
        biA[r] = biB[r];
        tvA[r] = tvB[r];
        pvA[r] = pvB[r];
        ppA[r] = ppB[r];
        csA[r] = csB[r];
        ptA[r] = ptB[r];
      }
    }
  }
}

extern "C" void kernel_launch(void* const* d_in, const int* in_sizes, int n_in,
                              void* d_out, int out_size, void* d_ws,
                              size_t ws_size, hipStream_t stream) {
  const float* t = (const float*)d_in[0];
  const float2* pos = (const float2*)d_in[1];
  const float* poi_t = (const float*)d_in[2];
  const float2* poi_pos = (const float2*)d_in[3];
  const int* batch = (const int*)d_in[4];
  const float* W1 = (const float*)d_in[5];
  const float* B1 = (const float*)d_in[6];
  const float* W2 = (const float*)d_in[7];
  const float* B2 = (const float*)d_in[8];
  const float* W3 = (const float*)d_in[9];
  const float* B3 = (const float*)d_in[10];
  const float* W4 = (const float*)d_in[11];
  const float* B4 = (const float*)d_in[12];
  const float* W5 = (const float*)d_in[13];
  const float* B5 = (const float*)d_in[14];
  float* out = (float*)d_out;

  float* csum = (float*)d_ws;                  // [NB*2]
  uint2* Wf = (uint2*)(csum + 2 * NB);         // [448]

  // prepack blocks 0-2 pack weights; blocks 3-66 zero csum + out.
  prepack_kernel<<<67, 256, 0, stream>>>(W1, W2, W3, W4, W5, B1, B2, B3, B4,
                                         B5, Wf, csum, out);
  centroid_kernel<<<GRIDP, 256, 0, stream>>>(pos, batch, csum);
  main_kernel<<<GRIDP, 256, 0, stream>>>(t, pos, poi_t, poi_pos, batch,
                                         (const float2*)csum, Wf, out);
}

// Round 17
// 50.285 us; speedup vs baseline: 1.2310x; 1.2310x over previous
//
#include <hip/hip_runtime.h>

#define NN 4194304
#define NB 16384

typedef _Float16 half4 __attribute__((ext_vector_type(4)));
typedef float floatx4 __attribute__((ext_vector_type(4)));
typedef unsigned int uint;

__device__ __forceinline__ uint pk_u32(float lo, float hi) {
  return __builtin_bit_cast(uint, __builtin_amdgcn_cvt_pkrtz(lo, hi));
}

__device__ __forceinline__ float f16_lo(uint u) {
  return (float)__builtin_bit_cast(_Float16, (unsigned short)(u & 0xffffu));
}
__device__ __forceinline__ float f16_hi(uint u) {
  return (float)__builtin_bit_cast(_Float16, (unsigned short)(u >> 16));
}

__device__ __forceinline__ half4 relu_cvt(floatx4 d) {
  uint2 u;
  u.x = pk_u32(d[0], d[1]);
  u.y = pk_u32(d[2], d[3]);
  half4 h = __builtin_bit_cast(half4, u);
  return __builtin_elementwise_max(h, half4{0, 0, 0, 0});
}

// DPP butterfly wave64 sum; total lands in lane 63. 6 VALU adds, no LDS.
template <int CTRL>
__device__ __forceinline__ float dpp_add(float x) {
  int y = __builtin_amdgcn_update_dpp(0, __builtin_bit_cast(int, x), CTRL,
                                      0xf, 0xf, true);
  return x + __builtin_bit_cast(float, y);
}
__device__ __forceinline__ float wave_sum(float x) {
  x = dpp_add<0x111>(x);
  x = dpp_add<0x112>(x);
  x = dpp_add<0x114>(x);
  x = dpp_add<0x118>(x);
  x = dpp_add<0x142>(x);
  x = dpp_add<0x143>(x);
  return x;
}

// Segmented reduce + atomics. Fast path: wave-uniform segment (avg run = 256).
__device__ __forceinline__ void seg_atomic_add2(int b, float vx, float vy,
                                                float* __restrict__ out) {
  const int lane = threadIdx.x & 63;
  int b0 = __builtin_amdgcn_readfirstlane(b);
  if (__ballot(b == b0) == ~0ull) {
    float sx = wave_sum(vx);
    float sy = wave_sum(vy);
    if (lane == 63) {
      atomicAdd(&out[2 * b0], sx);
      atomicAdd(&out[2 * b0 + 1], sy);
    }
    return;
  }
  int bprev = __shfl_up(b, 1);
  bool head = (lane == 0) || (b != bprev);
  unsigned long long hb = __ballot(head);
  unsigned long long mask_le = hb << (63 - lane);
  int run_start = lane - __clzll(mask_le);
  float sx = vx, sy = vy;
#pragma unroll
  for (int off = 1; off < 64; off <<= 1) {
    float ox = __shfl_up(sx, off);
    float oy = __shfl_up(sy, off);
    if (lane - off >= run_start) { sx += ox; sy += oy; }
  }
  int bnext = __shfl_down(b, 1);
  bool tail = (lane == 63) || (b != bnext);
  if (tail) {
    atomicAdd(&out[2 * b], sx);
    atomicAdd(&out[2 * b + 1], sy);
  }
}

// 4 nodes/thread: loads hoisted, stalls amortized. (R12/R14-proven shape.)
__global__ __launch_bounds__(256) void centroid_kernel(
    const float2* __restrict__ pos, const int* __restrict__ batch,
    float* __restrict__ csum) {
  int base = blockIdx.x * 1024 + threadIdx.x;
  int bi[4];
  float2 pv[4];
#pragma unroll
  for (int r = 0; r < 4; ++r) {
    bi[r] = batch[base + r * 256];
    pv[r] = pos[base + r * 256];
  }
#pragma unroll
  for (int r = 0; r < 4; ++r) seg_atomic_add2(bi[r], pv[r].x, pv[r].y, csum);
}

// Per-graph packed record: {poi_t, poi_pos.x, poi_pos.y, udc as 2xf16}
__global__ __launch_bounds__(256) void graphvec_kernel(
    const float* __restrict__ csum, const float2* __restrict__ poi_pos,
    const float* __restrict__ poi_t, float4* __restrict__ rec) {
  int i = blockIdx.x * 256 + threadIdx.x;
  float2 pp = poi_pos[i];
  float dcx = csum[2 * i] - pp.x;
  float dcy = csum[2 * i + 1] - pp.y;
  float inv = rsqrtf(dcx * dcx + dcy * dcy);
  uint udc = pk_u32(dcx * inv, dcy * inv);
  rec[i] = float4{poi_t[i], pp.x, pp.y, __builtin_bit_cast(float, udc)};
}

// Prepack weights into A-fragments of mfma_f32_16x16x16f16 (W as A: M=out,K=in).
// ALL biases folded via fake constant-1 neurons (see tile comments).
// Blocks 3..66 zero csum (8192 float4) and out (8192 float4).
__global__ void prepack_kernel(
    const float* __restrict__ W1, const float* __restrict__ W2,
    const float* __restrict__ W3, const float* __restrict__ W4,
    const float* __restrict__ W5, const float* __restrict__ B1,
    const float* __restrict__ B2, const float* __restrict__ B3,
    const float* __restrict__ B4, const float* __restrict__ B5,
    uint2* __restrict__ Wf, float* __restrict__ csum,
    float* __restrict__ out) {
  if (blockIdx.x >= 3) {
    int z = (blockIdx.x - 3) * 256 + threadIdx.x;  // 0..16383
    float4 zero{0.f, 0.f, 0.f, 0.f};
    if (z < 8192) ((float4*)csum)[z] = zero;
    else ((float4*)out)[z - 8192] = zero;
    return;
  }
  int p = blockIdx.x * 256 + threadIdx.x;
  if (p >= 448) return;
  int tile = p >> 6, lane = p & 63, row = lane & 15, kb = (lane >> 4) * 4;
  float v[4];
#pragma unroll
  for (int i = 0; i < 4; ++i) {
    int k = kb + i;
    float x = 0.f;
    switch (tile) {
      case 0:  // W1 (10x3); k=3: B1; row10 = bias-1 neuron
        if (row < 10 && k < 3) x = W1[row * 3 + k];
        if (k == 3) { if (row < 10) x = B1[row]; else if (row == 10) x = 1.f; }
        break;
      case 1:  // W2 rows 0-15; k=10: B2
        if (k < 10) x = W2[row * 10 + k];
        else if (k == 10) x = B2[row];
        break;
      case 2:  // W2 rows 16-19; k=10: B2[16+]; row4 = bias-1
        if (row < 4 && k < 10) x = W2[(16 + row) * 10 + k];
        if (k == 10) { if (row < 4) x = B2[16 + row]; else if (row == 4) x = 1.f; }
        break;
      case 3:  // W3 k0-15
        if (row < 10 && k < 16) x = W3[row * 20 + k];
        break;
      case 4:  // W3 k16-19; local k4: B3; row10 = bias-1
        if (row < 10 && k < 4) x = W3[row * 20 + 16 + k];
        if (k == 4) { if (row < 10) x = B3[row]; else if (row == 10) x = 1.f; }
        break;
      case 5:  // W4; k=10: B4; row5 = bias-1
        if (row < 5 && k < 10) x = W4[row * 10 + k];
        if (k == 10) { if (row < 5) x = B4[row]; else if (row == 5) x = 1.f; }
        break;
      default:  // W5; k=5: B5
        if (row == 0 && k < 5) x = W5[k];
        if (row == 0 && k == 5) x = B5[0];
        break;
    }
    v[i] = x;
  }
  Wf[p] = uint2{pk_u32(v[0], v[1]), pk_u32(v[2], v[3])};
}

__device__ __forceinline__ floatx4 mfma16(half4 a, half4 b, floatx4 c) {
  return __builtin_amdgcn_mfma_f32_16x16x16f16(a, b, c, 0, 0, 0);
}

// Single float4 gather per node-iteration (record packs poi_t/poi_pos/udc).
__global__ __launch_bounds__(256, 3) void main_kernel(
    const float* __restrict__ t, const float2* __restrict__ pos,
    const float4* __restrict__ rec, const int* __restrict__ batch,
    const uint2* __restrict__ Wf, float* __restrict__ out) {
  const int tid = threadIdx.x;
  const int lane = tid & 63;
  const int col = lane & 15;
  const int koct = lane >> 4;

  // ---- Phase 0: streaming loads + ONE gather per iteration upfront ----
  int base = blockIdx.x * 1024 + tid;
  int bi[4];
  float tvv[4];
  float2 pv[4];
#pragma unroll
  for (int r = 0; r < 4; ++r) {
    bi[r] = batch[base + r * 256];
    tvv[r] = t[base + r * 256];
    pv[r] = pos[base + r * 256];
  }
  float4 rc[4];
#pragma unroll
  for (int r = 0; r < 4; ++r) rc[r] = rec[bi[r]];

  // Weight A-fragments (all biases folded -> no C fragments).
  half4 wa[7];
#pragma unroll
  for (int k = 0; k < 7; ++k)
    wa[k] = __builtin_bit_cast(half4, Wf[k * 64 + lane]);
  floatx4 cz{0.f, 0.f, 0.f, 0.f};

  // ---- Phase 1: 2 passes x 2 iterations -> 8 MFMA chains per layer ----
#pragma unroll
  for (int rp = 0; rp < 2; ++rp) {
    float dpx[2], dpy[2], f1v[2], invr[2];
    int fx[2], fy[2];
#pragma unroll
    for (int u = 0; u < 2; ++u) {
      int r = rp * 2 + u;
      float f0 = tvv[r] - rc[r].x;
      uint uu_ = __builtin_bit_cast(uint, rc[r].w);
      float ucx = f16_lo(uu_);
      float ucy = f16_hi(uu_);
      dpx[u] = pv[r].x - rc[r].y;
      dpy[u] = pv[r].y - rc[r].z;
      f1v[u] = dpx[u] * dpx[u] + dpy[u] * dpy[u];
      invr[u] = rsqrtf(f1v[u]);
      float f2 = (dpx[u] * ucx + dpy[u] * ucy) * invr[u];
      fx[u] = (int)pk_u32(f0, f1v[u]);
      fy[u] = (int)pk_u32(f2, 1.0f);  // 1.0 feeds the folded-bias column
    }

    half4 b1[8];
#pragma unroll
    for (int u = 0; u < 2; ++u)
#pragma unroll
      for (int g = 0; g < 4; ++g) {
        int src = g * 16 + col;
        uint2 fr;
        fr.x = (uint)__shfl(fx[u], src);
        fr.y = (uint)__shfl(fy[u], src);
        b1[u * 4 + g] = __builtin_bit_cast(half4, fr);
      }

    floatx4 d[8];
    half4 a[8];
#pragma unroll
    for (int c = 0; c < 8; ++c) d[c] = mfma16(wa[0], b1[c], cz);  // L1
#pragma unroll
    for (int c = 0; c < 8; ++c) a[c] = relu_cvt(d[c]);

    floatx4 d2[8];
    half4 a3a[8], a3b[8];
#pragma unroll
    for (int c = 0; c < 8; ++c) d2[c] = mfma16(wa[1], a[c], cz);  // L2 M0-15
#pragma unroll
    for (int c = 0; c < 8; ++c) a3a[c] = relu_cvt(d2[c]);
#pragma unroll
    for (int c = 0; c < 8; ++c) d2[c] = mfma16(wa[2], a[c], cz);  // L2 M16-20
#pragma unroll
    for (int c = 0; c < 8; ++c) a3b[c] = relu_cvt(d2[c]);

#pragma unroll
    for (int c = 0; c < 8; ++c) d[c] = mfma16(wa[3], a3a[c], cz); // L3 k0-15
#pragma unroll
    for (int c = 0; c < 8; ++c) d[c] = mfma16(wa[4], a3b[c], d[c]); // L3 k16+
#pragma unroll
    for (int c = 0; c < 8; ++c) a[c] = relu_cvt(d[c]);

#pragma unroll
    for (int c = 0; c < 8; ++c) d[c] = mfma16(wa[5], a[c], cz);   // L4
#pragma unroll
    for (int c = 0; c < 8; ++c) a[c] = relu_cvt(d[c]);

#pragma unroll
    for (int c = 0; c < 8; ++c) d[c] = mfma16(wa[6], a[c], cz);   // L5

#pragma unroll
    for (int u = 0; u < 2; ++u) {
      float wg0 = __shfl(d[u * 4 + 0][0], col);
      float wg1 = __shfl(d[u * 4 + 1][0], col);
      float wg2 = __shfl(d[u * 4 + 2][0], col);
      float wg3 = __shfl(d[u * 4 + 3][0], col);
      float w = wg0;
      w = (koct == 1) ? wg1 : w;
      w = (koct == 2) ? wg2 : w;
      w = (koct == 3) ? wg3 : w;
      float invn = (f1v[u] > 0.f) ? invr[u] : 0.f;
      seg_atomic_add2(bi[rp * 2 + u], w * dpx[u] * invn, w * dpy[u] * invn,
                      out);
    }
  }
}

extern "C" void kernel_launch(void* const* d_in, const int* in_sizes, int n_in,
                              void* d_out, int out_size, void* d_ws,
                              size_t ws_size, hipStream_t stream) {
  const float* t = (const float*)d_in[0];
  const float2* pos = (const float2*)d_in[1];
  const float* poi_t = (const float*)d_in[2];
  const float2* poi_pos = (const float2*)d_in[3];
  const int* batch = (const int*)d_in[4];
  const float* W1 = (const float*)d_in[5];
  const float* B1 = (const float*)d_in[6];
  const float* W2 = (const float*)d_in[7];
  const float* B2 = (const float*)d_in[8];
  const float* W3 = (const float*)d_in[9];
  const float* B3 = (const float*)d_in[10];
  const float* W4 = (const float*)d_in[11];
  const float* B4 = (const float*)d_in[12];
  const float* W5 = (const float*)d_in[13];
  const float* B5 = (const float*)d_in[14];
  float* out = (float*)d_out;

  float* csum = (float*)d_ws;                  // [NB*2]
  float4* rec = (float4*)(csum + 2 * NB);      // [NB]
  uint2* Wf = (uint2*)(rec + NB);              // [448]

  // prepack blocks 0-2 pack weights; blocks 3-66 zero csum + out.
  prepack_kernel<<<67, 256, 0, stream>>>(W1, W2, W3, W4, W5, B1, B2, B3, B4,
                                         B5, Wf, csum, out);
  centroid_kernel<<<NN / 1024, 256, 0, stream>>>(pos, batch, csum);
  graphvec_kernel<<<NB / 256, 256, 0, stream>>>(csum, poi_pos, poi_t, rec);
  main_kernel<<<NN / 1024, 256, 0, stream>>>(t, pos, rec, batch, Wf, out);
}